// Round 5
// baseline (72.234 us; speedup 1.0000x reference)
//
#include <hip/hip_runtime.h>
#include <math.h>

#define LN_EPS 1e-5f
#define LOG2E  1.44269504088896340736f

typedef float vf4 __attribute__((ext_vector_type(4)));  // native clang vector:
                                                        // valid for nontemporal builtins

// ============================================================================
// Math (derived, exact):
//  - softmin cancels out of LayerNorm entirely (shift invariance; best <= min x).
//  - h_i = (mu - x_i)*rsqrt(var+eps)*lnw_i + lnb_i, and since sum(d_i) = 0,
//    layer1 pre-activation a_j = A0_j*t0 + A1_j*t1 + C_j with t_i = d_i*rs:
//       A0_j = w1[j][0]*lnw0 - w1[j][2]*lnw2
//       A1_j = w1[j][1]*lnw1 - w1[j][2]*lnw2
//       C_j  = w1[j].lnb + b1_j
//  - relu(u + C) = max(u, -C) + C ; the "+C" term folds into b2 via sum_j w2*C.
//  - log2e folds into w2,b2 so softmax uses exp2 (v_exp_f32) directly, and the
//    max-subtract is dropped (|logits*log2e| << 126, no overflow possible).
// ws layout (floats): A0[0..15] A1[16..31] negC[32..47]
//                     W2s[48+16c+j] (c<3,j<16)  B2s[96..98]
// ============================================================================

__global__ void nn2_setup(const float* __restrict__ lnw, const float* __restrict__ lnb,
                          const float* __restrict__ w1,  const float* __restrict__ b1,
                          const float* __restrict__ w2,  const float* __restrict__ b2,
                          float* __restrict__ ws)
{
    int t = threadIdx.x;
    if (t < 16) {
        float lw0 = lnw[0], lw1 = lnw[1], lw2 = lnw[2];
        float lb0 = lnb[0], lb1 = lnb[1], lb2 = lnb[2];
        float w10 = w1[3*t], w11 = w1[3*t+1], w12 = w1[3*t+2];
        ws[t]    = w10 * lw0 - w12 * lw2;
        ws[16+t] = w11 * lw1 - w12 * lw2;
        ws[32+t] = -(w10 * lb0 + w11 * lb1 + w12 * lb2 + b1[t]);
    }
    if (t < 48) ws[48+t] = w2[t] * LOG2E;
    if (t < 3) {
        float lb0 = lnb[0], lb1 = lnb[1], lb2 = lnb[2];
        float acc = b2[t];
        for (int j = 0; j < 16; ++j) {
            float c = w1[3*j]*lb0 + w1[3*j+1]*lb1 + w1[3*j+2]*lb2 + b1[j];
            acc = fmaf(w2[16*t+j], c, acc);
        }
        ws[96+t] = acc * LOG2E;
    }
}

// 8 rows per thread as two disjoint coalesced 4-row groups (g and g+T):
// 6x dwordx4 loads in flight per thread, weights amortized 8x, deep FMA ILP.
__global__ __launch_bounds__(256) void nn2_main(
    const float* __restrict__ x, const float* __restrict__ ws,
    float* __restrict__ out, int nrows, int T /* total threads */)
{
    int g = blockIdx.x * blockDim.x + threadIdx.x;
    if (g >= T) return;
    long long baseA = (long long)g * 4;
    long long baseB = baseA + (long long)T * 4;
    if (baseA >= nrows) return;
    const bool fullA = (baseA + 4 <= nrows);
    const bool fullB = (baseB + 4 <= nrows);
    const bool anyB  = (baseB < nrows);

    const vf4* x4 = reinterpret_cast<const vf4*>(x);

    float X[8][3];
#pragma unroll
    for (int r = 0; r < 8; ++r) { X[r][0] = 0.f; X[r][1] = 0.f; X[r][2] = 0.f; }

    if (fullA) {
        vf4 va = __builtin_nontemporal_load(&x4[(long long)g*3 + 0]);
        vf4 vb = __builtin_nontemporal_load(&x4[(long long)g*3 + 1]);
        vf4 vc = __builtin_nontemporal_load(&x4[(long long)g*3 + 2]);
        X[0][0]=va.x; X[0][1]=va.y; X[0][2]=va.z;
        X[1][0]=va.w; X[1][1]=vb.x; X[1][2]=vb.y;
        X[2][0]=vb.z; X[2][1]=vb.w; X[2][2]=vc.x;
        X[3][0]=vc.y; X[3][1]=vc.z; X[3][2]=vc.w;
    } else {
        for (int r = 0; r < 4 && baseA + r < nrows; ++r) {
            long long q = baseA + r;
            X[r][0]=x[3*q]; X[r][1]=x[3*q+1]; X[r][2]=x[3*q+2];
        }
    }
    if (fullB) {
        long long gb = (long long)(g + T) * 3;
        vf4 va = __builtin_nontemporal_load(&x4[gb + 0]);
        vf4 vb = __builtin_nontemporal_load(&x4[gb + 1]);
        vf4 vc = __builtin_nontemporal_load(&x4[gb + 2]);
        X[4][0]=va.x; X[4][1]=va.y; X[4][2]=va.z;
        X[5][0]=va.w; X[5][1]=vb.x; X[5][2]=vb.y;
        X[6][0]=vb.z; X[6][1]=vb.w; X[6][2]=vc.x;
        X[7][0]=vc.y; X[7][1]=vc.z; X[7][2]=vc.w;
    } else if (anyB) {
        for (int r = 0; r < 4 && baseB + r < nrows; ++r) {
            long long q = baseB + r;
            X[4+r][0]=x[3*q]; X[4+r][1]=x[3*q+1]; X[4+r][2]=x[3*q+2];
        }
    }

    // ---- LayerNorm core: t0,t1 per row ----
    float t0[8], t1[8];
#pragma unroll
    for (int r = 0; r < 8; ++r) {
        float x0 = X[r][0], x1 = X[r][1], x2 = X[r][2];
        float mu = (x0 + x1 + x2) * (1.0f/3.0f);
        float d0 = mu - x0, d1 = mu - x1, d2 = mu - x2;
        float sse = fmaf(d0, d0, fmaf(d1, d1, d2 * d2));
        float rs  = __builtin_amdgcn_rsqf(fmaf(sse, 1.0f/3.0f, LN_EPS));
        t0[r] = d0 * rs;
        t1[r] = d1 * rs;
    }

    // ---- fused MLP: logits (log2 domain) ----
    float l[8][3];
    {
        const float B0 = ws[96], B1 = ws[97], B2 = ws[98];
#pragma unroll
        for (int r = 0; r < 8; ++r) { l[r][0] = B0; l[r][1] = B1; l[r][2] = B2; }
    }
#pragma unroll
    for (int j = 0; j < 16; ++j) {
        const float A0 = ws[j];
        const float A1 = ws[16+j];
        const float nC = ws[32+j];
        const float u0 = ws[48+j];
        const float u1 = ws[64+j];
        const float u2 = ws[80+j];
#pragma unroll
        for (int r = 0; r < 8; ++r) {
            float a = fmaf(A1, t1[r], A0 * t0[r]);
            float m = fmaxf(a, nC);
            l[r][0] = fmaf(m, u0, l[r][0]);
            l[r][1] = fmaf(m, u1, l[r][1]);
            l[r][2] = fmaf(m, u2, l[r][2]);
        }
    }

    // ---- softmax (exp2 domain, no max-subtract) + weighted sum ----
    float O[8];
#pragma unroll
    for (int r = 0; r < 8; ++r) {
        float e0 = __builtin_amdgcn_exp2f(l[r][0]);
        float e1 = __builtin_amdgcn_exp2f(l[r][1]);
        float e2 = __builtin_amdgcn_exp2f(l[r][2]);
        float rc = __builtin_amdgcn_rcpf(e0 + e1 + e2);
        O[r] = fmaf(X[r][0], e0, fmaf(X[r][1], e1, X[r][2] * e2)) * rc;
    }

    vf4* out4 = reinterpret_cast<vf4*>(out);
    if (fullA) {
        vf4 o; o.x=O[0]; o.y=O[1]; o.z=O[2]; o.w=O[3];
        __builtin_nontemporal_store(o, &out4[g]);
    } else {
        for (int r = 0; r < 4 && baseA + r < nrows; ++r) out[baseA + r] = O[r];
    }
    if (fullB) {
        vf4 o; o.x=O[4]; o.y=O[5]; o.z=O[6]; o.w=O[7];
        __builtin_nontemporal_store(o, &out4[g + T]);
    } else if (anyB) {
        for (int r = 0; r < 4 && baseB + r < nrows; ++r) out[baseB + r] = O[4+r];
    }
}

// Fallback (ws too small): R3's proven self-contained kernel.
__global__ __launch_bounds__(256) void nn2_fallback(
    const float* __restrict__ x,
    const float* __restrict__ lnw_g, const float* __restrict__ lnb_g,
    const float* __restrict__ w1_g,  const float* __restrict__ b1_g,
    const float* __restrict__ w2_g,  const float* __restrict__ b2_g,
    float* __restrict__ out, int nrows)
{
    int g = blockIdx.x * blockDim.x + threadIdx.x;
    long long base = (long long)g * 4;
    if (base >= nrows) return;
    const float lw0 = lnw_g[0], lw1 = lnw_g[1], lw2 = lnw_g[2];
    const float lb0 = lnb_g[0], lb1 = lnb_g[1], lb2 = lnb_g[2];
    float X[4][3];
    if (base + 4 <= nrows) {
        const float4* x4 = reinterpret_cast<const float4*>(x) + (long long)g * 3;
        float4 va = x4[0], vb = x4[1], vc = x4[2];
        X[0][0]=va.x; X[0][1]=va.y; X[0][2]=va.z;
        X[1][0]=va.w; X[1][1]=vb.x; X[1][2]=vb.y;
        X[2][0]=vb.z; X[2][1]=vb.w; X[2][2]=vc.x;
        X[3][0]=vc.y; X[3][1]=vc.z; X[3][2]=vc.w;
    } else {
        for (int r = 0; r < 4; ++r) {
            long long rr = (base + r < nrows) ? base + r : (long long)nrows - 1;
            X[r][0]=x[rr*3]; X[r][1]=x[rr*3+1]; X[r][2]=x[rr*3+2];
        }
    }
    float H[4][3];
#pragma unroll
    for (int r = 0; r < 4; ++r) {
        float x0=X[r][0], x1=X[r][1], x2=X[r][2];
        float mu=(x0+x1+x2)*(1.0f/3.0f);
        float d0=mu-x0, d1=mu-x1, d2=mu-x2;
        float rs=__builtin_amdgcn_rsqf(fmaf(fmaf(d0,d0,fmaf(d1,d1,d2*d2)),1.0f/3.0f,LN_EPS));
        H[r][0]=fmaf(d0*rs,lw0,lb0); H[r][1]=fmaf(d1*rs,lw1,lb1); H[r][2]=fmaf(d2*rs,lw2,lb2);
    }
    float L[4][3];
    { const float b20=b2_g[0],b21=b2_g[1],b22=b2_g[2];
#pragma unroll
      for (int r=0;r<4;++r){L[r][0]=b20;L[r][1]=b21;L[r][2]=b22;} }
#pragma unroll
    for (int j = 0; j < 16; ++j) {
        const float a0=w1_g[3*j],a1=w1_g[3*j+1],a2=w1_g[3*j+2],bj=b1_g[j];
        const float u0=w2_g[j],u1=w2_g[16+j],u2=w2_g[32+j];
#pragma unroll
        for (int r=0;r<4;++r){
            float hj=fmaf(H[r][2],a2,fmaf(H[r][1],a1,fmaf(H[r][0],a0,bj)));
            hj=fmaxf(hj,0.0f);
            L[r][0]=fmaf(hj,u0,L[r][0]); L[r][1]=fmaf(hj,u1,L[r][1]); L[r][2]=fmaf(hj,u2,L[r][2]);
        }
    }
    float O[4];
#pragma unroll
    for (int r=0;r<4;++r){
        float l0=L[r][0],l1=L[r][1],l2=L[r][2];
        float lm=fmaxf(l0,fmaxf(l1,l2));
        float s0=__expf(l0-lm),s1=__expf(l1-lm),s2=__expf(l2-lm);
        float rc=__builtin_amdgcn_rcpf(s0+s1+s2);
        O[r]=fmaf(X[r][0],s0,fmaf(X[r][1],s1,X[r][2]*s2))*rc;
    }
    if (base + 4 <= nrows) {
        float4 o; o.x=O[0];o.y=O[1];o.z=O[2];o.w=O[3];
        reinterpret_cast<float4*>(out)[g] = o;
    } else {
        for (int r = 0; r < 4 && base + r < nrows; ++r) out[base + r] = O[r];
    }
}

extern "C" void kernel_launch(void* const* d_in, const int* in_sizes, int n_in,
                              void* d_out, int out_size, void* d_ws, size_t ws_size,
                              hipStream_t stream) {
    const float* x    = (const float*)d_in[0];
    const float* lnw  = (const float*)d_in[1];
    const float* lnb  = (const float*)d_in[2];
    const float* w1   = (const float*)d_in[3];
    const float* b1   = (const float*)d_in[4];
    const float* w2   = (const float*)d_in[5];
    const float* b2   = (const float*)d_in[6];
    // d_in[7] (log_tau) is mathematically dead: softmin cancels in LayerNorm.
    float* out = (float*)d_out;
    int nrows = out_size;

    if (ws_size >= 99 * sizeof(float)) {
        float* ws = (float*)d_ws;
        nn2_setup<<<1, 64, 0, stream>>>(lnw, lnb, w1, b1, w2, b2, ws);
        int T    = (nrows + 7) / 8;            // 8 rows per thread
        int grid = (T + 255) / 256;
        nn2_main<<<grid, 256, 0, stream>>>(x, ws, out, nrows, T);
    } else {
        int ngroups = (nrows + 3) / 4;
        int grid    = (ngroups + 255) / 256;
        nn2_fallback<<<grid, 256, 0, stream>>>(x, lnw, lnb, w1, b1, w2, b2, out, nrows);
    }
}